// Round 1
// baseline (201.561 us; speedup 1.0000x reference)
//
#include <hip/hip_runtime.h>
#include <hip/hip_bf16.h>

#define V     8192
#define E_N   262144
#define NN    262144
#define D     128
#define KDIM  8192

typedef __attribute__((ext_vector_type(8))) short b16x8;
typedef __attribute__((ext_vector_type(8))) unsigned short u16x8;
typedef __attribute__((ext_vector_type(4))) float f32x4;
typedef __attribute__((ext_vector_type(4))) unsigned int u32x4;

static __device__ __forceinline__ unsigned short f2bf(float f) {
    union { float f; unsigned int u; } v; v.f = f;
    unsigned int r = v.u + 0x7FFFu + ((v.u >> 16) & 1u);   // RNE
    return (unsigned short)(r >> 16);
}

// ---- W [K][D] fp32 -> WbT [D][K] bf16 (transposed, for contiguous B staging) ----
__global__ void k_wbt(const float* __restrict__ W, unsigned short* __restrict__ WbT) {
    __shared__ float tile[32][33];
    int bk = blockIdx.x & 255;      // K/32
    int bn = blockIdx.x >> 8;       // D/32
    int r = threadIdx.x >> 5;       // 0..7
    int c = threadIdx.x & 31;
    int k0 = bk * 32, n0 = bn * 32;
    for (int i = 0; i < 4; i++)
        tile[r + 8 * i][c] = W[(size_t)(k0 + r + 8 * i) * D + n0 + c];
    __syncthreads();
    for (int i = 0; i < 4; i++)
        WbT[(size_t)(n0 + r + 8 * i) * KDIM + k0 + c] = f2bf(tile[c][r + 8 * i]);
}

// ---- H := broadcast(b) (GEMM partials atomically accumulate on top) ----
__global__ void k_initH(float* __restrict__ H, const float* __restrict__ b) {
    int t = blockIdx.x * 256 + threadIdx.x;       // over V*D
    H[t] = b[t & (D - 1)];
}

// ---- degree histogram over dst ----
__global__ void k_hist(const int* __restrict__ dst, int* __restrict__ hist) {
    int e = blockIdx.x * 256 + threadIdx.x;
    if (e < E_N) atomicAdd(&hist[dst[e]], 1);
}

// ---- exclusive scan of 8192 counts, single block ----
__global__ void k_scan(const int* __restrict__ hist, int* __restrict__ offsets,
                       int* __restrict__ cursor) {
    __shared__ int part[1024];
    int t = threadIdx.x;
    int base = t * 8;
    int loc[8]; int s = 0;
    for (int i = 0; i < 8; i++) { loc[i] = s; s += hist[base + i]; }
    part[t] = s;
    __syncthreads();
    for (int st = 1; st < 1024; st <<= 1) {
        int v = (t >= st) ? part[t - st] : 0;
        __syncthreads();
        part[t] += v;
        __syncthreads();
    }
    int ex = (t == 0) ? 0 : part[t - 1];
    for (int i = 0; i < 8; i++) {
        int o = ex + loc[i];
        offsets[base + i] = o;
        cursor[base + i] = o;
    }
    if (t == 1023) offsets[8192] = ex + s;
}

// ---- scatter edges into CSR-by-dst ----
__global__ void k_scatter(const int* __restrict__ srcI, const int* __restrict__ dstI,
                          const float* __restrict__ w, int* __restrict__ cursor,
                          int* __restrict__ src_s, float* __restrict__ w_s) {
    int e = blockIdx.x * 256 + threadIdx.x;
    if (e < E_N) {
        int dnode = dstI[e];
        int pos = atomicAdd(&cursor[dnode], 1);
        src_s[pos] = srcI[e];
        w_s[pos]  = w[e];
    }
}

// ---- H += A@W : bf16 MFMA, BM=64, BN=128, BK=64, split-K=4 ----
__global__ void __launch_bounds__(256) k_gemm(const float* __restrict__ A,
                                              const unsigned short* __restrict__ WbT,
                                              float* __restrict__ H) {
    __shared__ unsigned short As[64][72];     // +8 pad breaks bank stride
    __shared__ unsigned short Bs[128][72];

    int rb = blockIdx.x >> 2;      // 0..127 row block
    int ks = blockIdx.x & 3;       // K split
    int tid = threadIdx.x;
    int wave = tid >> 6, lane = tid & 63;
    int r16 = lane & 15, kg = lane >> 4;

    int arow = tid >> 2, ak0 = (tid & 3) * 16;     // A staging: 16 floats/thread
    int brow = tid >> 1, bk0 = (tid & 1) * 32;     // B staging: 32 bf16/thread

    const float* aPtr = A + (size_t)(rb * 64 + arow) * KDIM + ks * 2048 + ak0;
    const unsigned short* bPtr = WbT + (size_t)brow * KDIM + ks * 2048 + bk0;

    f32x4 acc[8];
    f32x4 zero = {0.f, 0.f, 0.f, 0.f};
    for (int t = 0; t < 8; t++) acc[t] = zero;

    for (int kk = 0; kk < 32; kk++) {
        f32x4 av[4];
        u32x4 bv[4];
        #pragma unroll
        for (int i = 0; i < 4; i++) av[i] = *(const f32x4*)(aPtr + i * 4);
        #pragma unroll
        for (int i = 0; i < 4; i++) bv[i] = *(const u32x4*)(bPtr + i * 8);
        aPtr += 64; bPtr += 64;

        __syncthreads();   // previous tile fully consumed
        u16x8 p0, p1;
        #pragma unroll
        for (int j = 0; j < 4; j++) {
            p0[j]     = f2bf(av[0][j]);  p0[j + 4] = f2bf(av[1][j]);
            p1[j]     = f2bf(av[2][j]);  p1[j + 4] = f2bf(av[3][j]);
        }
        *(u16x8*)&As[arow][ak0]     = p0;
        *(u16x8*)&As[arow][ak0 + 8] = p1;
        #pragma unroll
        for (int i = 0; i < 4; i++) *(u32x4*)&Bs[brow][bk0 + i * 8] = bv[i];
        __syncthreads();

        #pragma unroll
        for (int s = 0; s < 2; s++) {
            b16x8 af = *(const b16x8*)&As[wave * 16 + r16][s * 32 + kg * 8];
            #pragma unroll
            for (int t = 0; t < 8; t++) {
                b16x8 bf = *(const b16x8*)&Bs[t * 16 + r16][s * 32 + kg * 8];
                acc[t] = __builtin_amdgcn_mfma_f32_16x16x32_bf16(af, bf, acc[t], 0, 0, 0);
            }
        }
    }

    int rbase = rb * 64 + wave * 16 + kg * 4;
    #pragma unroll
    for (int t = 0; t < 8; t++) {
        int col = t * 16 + r16;
        #pragma unroll
        for (int j = 0; j < 4; j++)
            atomicAdd(&H[(size_t)(rbase + j) * D + col], acc[t][j]);
    }
}

// ---- emb = 0.8*P + 0.2*H, L2-normalize per row (V rows) ----
__global__ void k_emb(const float* __restrict__ H, const int* __restrict__ offsets,
                      const int* __restrict__ src_s, const float* __restrict__ w_s,
                      float* __restrict__ embn) {
    __shared__ float red[128];
    int v = blockIdx.x;
    int d = threadIdx.x;
    int s0 = offsets[v], s1 = offsets[v + 1];
    float acc = 0.f;
    for (int i = s0; i < s1; i++) {
        int s = src_s[i];
        float w = w_s[i];
        acc = fmaf(w, H[(size_t)s * D + d], acc);
    }
    float e = 0.8f * acc + 0.2f * H[(size_t)v * D + d];
    red[d] = e * e;
    __syncthreads();
    for (int st = 64; st > 0; st >>= 1) {
        if (d < st) red[d] += red[d + st];
        __syncthreads();
    }
    float norm = sqrtf(red[0]);
    float scale = 1.f / fmaxf(norm, 1e-12f);
    embn[(size_t)v * D + d] = e * scale;
}

// ---- out[n] = embn[x[n]] (float4 copy) ----
__global__ void k_out(const int* __restrict__ x, const float* __restrict__ embn,
                      float* __restrict__ out) {
    int t = blockIdx.x * 256 + threadIdx.x;   // over NN * 32
    int n = t >> 5, c = t & 31;
    int xv = x[n];
    ((f32x4*)out)[t] = ((const f32x4*)embn)[xv * 32 + c];
}

extern "C" void kernel_launch(void* const* d_in, const int* in_sizes, int n_in,
                              void* d_out, int out_size, void* d_ws, size_t ws_size,
                              hipStream_t stream) {
    const int*   x      = (const int*)d_in[0];
    const int*   eSrc   = (const int*)d_in[1];          // edge_index[0]
    const int*   eDst   = ((const int*)d_in[1]) + E_N;  // edge_index[1]
    const float* eW     = (const float*)d_in[2];
    const float* A      = (const float*)d_in[3];        // embedding [V][V]
    const float* W      = (const float*)d_in[4];        // [V][D]
    const float* b      = (const float*)d_in[5];        // [D]
    float* out = (float*)d_out;

    char* ws = (char*)d_ws;
    unsigned short* WbT = (unsigned short*)(ws);                       // 2 MB
    float* H            = (float*)(ws + (2u << 20));                   // 4 MB
    float* embn         = (float*)(ws + (6u << 20));                   // 4 MB
    int* offsets        = (int*)(ws + (10u << 20));                    // 8193 ints
    int* cursor         = (int*)(ws + (10u << 20) + 40960);           // 8192 ints (also hist)
    int* src_s          = (int*)(ws + (10u << 20) + 131072);          // 1 MB
    float* w_s          = (float*)(ws + (10u << 20) + 131072 + (1u << 20)); // 1 MB

    hipMemsetAsync(cursor, 0, V * sizeof(int), stream);
    k_wbt    <<<1024, 256, 0, stream>>>(W, WbT);
    k_initH  <<<(V * D) / 256, 256, 0, stream>>>(H, b);
    k_hist   <<<E_N / 256, 256, 0, stream>>>(eDst, cursor);
    k_scan   <<<1, 1024, 0, stream>>>(cursor, offsets, cursor);
    k_scatter<<<E_N / 256, 256, 0, stream>>>(eSrc, eDst, eW, cursor, src_s, w_s);
    k_gemm   <<<512, 256, 0, stream>>>(A, WbT, H);
    k_emb    <<<V, D, 0, stream>>>(H, offsets, src_s, w_s, embn);
    k_out    <<<(NN * 32) / 256, 256, 0, stream>>>(x, embn, out);
}